// Round 14
// baseline (74.758 us; speedup 1.0000x reference)
//
#include <hip/hip_runtime.h>
#include <stdint.h>

#define BS   16384
#define XRW  768
#define HD   256
#define DIN  1280
#define N4   1024
#define NKT  20   // 1280 / 64 K-tiles

typedef __attribute__((ext_vector_type(4))) float f32x4;
typedef __attribute__((ext_vector_type(8))) short s16x8;
typedef __attribute__((ext_vector_type(4))) unsigned int u32x4;

__device__ __forceinline__ unsigned short f2bf(float f) {
  uint32_t u = __builtin_bit_cast(uint32_t, f);
  u += 0x7FFFu + ((u >> 16) & 1u);   // RNE
  return (unsigned short)(u >> 16);
}
__device__ __forceinline__ uint32_t cvtpk(float a, float b) {
  uint32_t d;
  asm("v_cvt_pk_bf16_f32 %0, %1, %2" : "=v"(d) : "v"(a), "v"(b));
  return d;
}
__device__ __forceinline__ float sigmoidf_(float x) {
  return 1.0f / (1.0f + __expf(-x));
}
__device__ __forceinline__ float tanhf_(float x) {
  return 1.0f - 2.0f / (__expf(2.0f * x) + 1.0f);
}
__device__ __forceinline__ void gload16(const void* g, void* l) {
  __builtin_amdgcn_global_load_lds((const __attribute__((address_space(1))) void*)g,
                                   (__attribute__((address_space(3))) void*)l, 16, 0, 0);
}

// ---- Wt[n'][k] bf16 row-major; n' = (h>>4)*64 + g*16 + (h&15).
// LDS-tiled transpose (R13, verified): b = g + 4*(kt + 20*ht).
__global__ __launch_bounds__(256) void conv_w_kernel(const float* __restrict__ Wi,
                                                     const float* __restrict__ Wf,
                                                     const float* __restrict__ Wo,
                                                     const float* __restrict__ Ws,
                                                     unsigned short* __restrict__ Wt) {
  __shared__ float tile[64][65];
  const int b  = blockIdx.x;
  const int g  = b & 3;                 // gate
  const int t  = b >> 2;                // [0,80)
  const int k0 = (t % 20) * 64;         // k-tile base
  const int h0 = (t / 20) * 64;         // h-tile base
  const float* W = (g == 0) ? Wi : (g == 1) ? Wf : (g == 2) ? Wo : Ws;

  const int tr = threadIdx.x >> 4;            // 0..15
  const int tc = (threadIdx.x & 15) * 4;      // 0..60
  #pragma unroll
  for (int rr = 0; rr < 4; ++rr) {
    const int r = rr * 16 + tr;
    f32x4 v = *(const f32x4*)(W + (size_t)(k0 + r) * HD + h0 + tc);
    tile[r][tc + 0] = v.x; tile[r][tc + 1] = v.y;
    tile[r][tc + 2] = v.z; tile[r][tc + 3] = v.w;
  }
  __syncthreads();

  const int hl = threadIdx.x >> 2;            // 0..63 local h
  const int kc = (threadIdx.x & 3) * 16;      // 0..48 local k chunk
  const int h  = h0 + hl;
  const int np = (h >> 4) * 64 + g * 16 + (h & 15);
  s16x8 o0, o1;
  #pragma unroll
  for (int j = 0; j < 8; ++j) {
    o0[j] = (short)f2bf(tile[kc + j][hl]);
    o1[j] = (short)f2bf(tile[kc + 8 + j][hl]);
  }
  *(s16x8*)(Wt + (size_t)np * DIN + k0 + kc)     = o0;
  *(s16x8*)(Wt + (size_t)np * DIN + k0 + kc + 8) = o1;
}

// ---- 128x128 tile, BK=64, 4 waves (2M x 2N, wave 64x64), 2-buffer LDS
// (A 2x16K + B 2x16K = 64K) -> 2 RESIDENT BLOCKS/CU: independent barrier
// domains fill each other's drain/latency holes (m114; m103: 128^2 > 256^2
// at the m97-class structure). K-loop rhythm identical to the R9 champion:
// issue-early A regs, async B gload_lds, mid vmcnt(4), end vmcnt(0), one
// barrier + publish-lgkm0 per tile, unpinned ds_read->MFMA, register epilogue.
__global__ __launch_bounds__(256, 2)
void lstm_gemm_kernel(const float* __restrict__ X,
                      const float* __restrict__ PT,
                      const float* __restrict__ PL,
                      const unsigned short* __restrict__ Wt,
                      const float* __restrict__ BI,
                      const float* __restrict__ BF,
                      const float* __restrict__ BO,
                      const float* __restrict__ BSv,
                      const float* __restrict__ OLD,
                      float* __restrict__ out) {
  __shared__ unsigned char smem[65536];  // A: 2x16KB @0; B: 2x16KB @32K
  const int tid  = threadIdx.x;
  const int wid  = tid >> 6;
  const int lane = tid & 63;

  // T1: XCD owns 16 contiguous M-panels x all 8 N-tiles (1024 = 8 x 128).
  const int H = blockIdx.x;
  const int xcd = H & 7, slot = H >> 3;          // slot in [0,128)
  const int mt = xcd * 16 + (slot >> 3);         // [0,128)
  const int nt = slot & 7;                       // [0,8)
  const int wr = wid >> 1, wc = wid & 1;

  // ---- B staging (gload_lds, linear LDS dest, pre-swizzled source col)
  const int r8   = tid >> 3;                     // 0..31 (row within 32-row chunk)
  const int scol = ((tid & 7) ^ (r8 & 7)) << 4;
  const char* gB = (const char*)Wt + (size_t)(nt * 128 + r8) * (DIN * 2) + scol;

#define STAGE_B(t1, oB) do {                                                  \
    const int kb_ = (t1) * 128;                                               \
    _Pragma("unroll")                                                         \
    for (int c_ = 0; c_ < 4; ++c_)                                            \
      gload16(gB + (size_t)c_ * (32 * DIN * 2) + kb_,                         \
              &smem[32768 + (oB) + c_ * 4096 + tid * 16]);                    \
  } while (0)

  // ---- A reg staging: half h covers rows h*64 + {arow, arow+32}
  const int arow  = tid >> 3;                    // 0..31
  const int a7    = tid & 7;
  const int awcol = ((a7 ^ (arow & 7)) << 4);

#define ALOAD(t1, h, R0, R1, R2, R3) do {                                     \
    const float* asrc_; int astr_, aoff_;                                     \
    if ((t1) < 12)      { asrc_ = X;  astr_ = XRW; aoff_ = (t1) * 64; }       \
    else if ((t1) < 16) { asrc_ = PT; astr_ = HD;  aoff_ = ((t1) - 12) * 64; }\
    else                { asrc_ = PL; astr_ = HD;  aoff_ = ((t1) - 16) * 64; }\
    const float* ga_ = asrc_ + (size_t)(mt * 128 + arow + (h) * 64) * astr_   \
                             + aoff_ + a7 * 8;                                \
    R0 = *(const f32x4*)(ga_);                                                \
    R1 = *(const f32x4*)(ga_ + 4);                                            \
    R2 = *(const f32x4*)(ga_ + (size_t)32 * astr_);                           \
    R3 = *(const f32x4*)(ga_ + (size_t)32 * astr_ + 4);                       \
  } while (0)

#define AWRITE(oB, h, R0, R1, R2, R3) do {                                    \
    u32x4 w0_, w1_;                                                           \
    w0_.x = cvtpk(R0.x, R0.y); w0_.y = cvtpk(R0.z, R0.w);                     \
    w0_.z = cvtpk(R1.x, R1.y); w0_.w = cvtpk(R1.z, R1.w);                     \
    w1_.x = cvtpk(R2.x, R2.y); w1_.y = cvtpk(R2.z, R2.w);                     \
    w1_.z = cvtpk(R3.x, R3.y); w1_.w = cvtpk(R3.z, R3.w);                     \
    *(u32x4*)(&smem[(oB) + ((arow + (h) * 64)      << 7) + awcol]) = w0_;     \
    *(u32x4*)(&smem[(oB) + ((arow + (h) * 64 + 32) << 7) + awcol]) = w1_;     \
  } while (0)

  // ---- frag read addressing (row&7 == lane&7 for all frags; conflict-free)
  const int rx   = lane & 15;
  const int axor = (lane & 7) << 4;
  const int col0 = (((lane >> 4) << 4)) ^ axor;        // kh=0
  const int col1 = (64 + ((lane >> 4) << 4)) ^ axor;   // kh=1
  const int aRow = (wr * 64 + rx) * 128;               // + bufA + mf*2048
  const int bRow = 32768 + (wc * 64 + rx) * 128;       // + bufB + nf*2048

  f32x4 acc[4][4];
  #pragma unroll
  for (int i = 0; i < 4; ++i)
    #pragma unroll
    for (int j = 0; j < 4; ++j) {
      f32x4 z = {0.0f, 0.0f, 0.0f, 0.0f};
      acc[i][j] = z;
    }

#define VMW(N) asm volatile("s_waitcnt vmcnt(" #N ")" ::: "memory")
#define LGKM0() do { asm volatile("s_waitcnt lgkmcnt(0)" ::: "memory");       \
                     __builtin_amdgcn_sched_barrier(0); } while (0)
  // bq FIRST: first MFMA needs bq[0..3]+aq[0]; remaining aq reads hide
  // under the MFMA stream (compiler emits per-register lgkmcnt).
#define FRAGS(bo_, kh_col) do {                                               \
    _Pragma("unroll")                                                         \
    for (int nf = 0; nf < 4; ++nf)                                            \
      bq[nf] = *(const s16x8*)(&smem[(bo_) + bRow + nf * 2048 + (kh_col)]);   \
    _Pragma("unroll")                                                         \
    for (int mf = 0; mf < 4; ++mf)                                            \
      aq[mf] = *(const s16x8*)(&smem[(bo_) + aRow + mf * 2048 + (kh_col)]);   \
  } while (0)
#define MFMAS() do {                                                          \
    __builtin_amdgcn_s_setprio(1);                                            \
    _Pragma("unroll")                                                         \
    for (int mf = 0; mf < 4; ++mf)                                            \
      _Pragma("unroll")                                                       \
      for (int nf = 0; nf < 4; ++nf)                                          \
        acc[mf][nf] = __builtin_amdgcn_mfma_f32_16x16x32_bf16(aq[mf], bq[nf], \
                                                      acc[mf][nf], 0, 0, 0);  \
    __builtin_amdgcn_s_setprio(0);                                            \
  } while (0)

  // ---- prologue: fill buf0 with tile 0 (A via regs+cvt, B via gload_lds)
  {
    f32x4 p0, p1, p2, p3;
    ALOAD(0, 0, p0, p1, p2, p3);
    STAGE_B(0, 0);
    VMW(4);        // A H0 regs landed (B(0) in flight)
    AWRITE(0, 0, p0, p1, p2, p3);
    ALOAD(0, 1, p0, p1, p2, p3);
    VMW(0);        // A H1 + B(0) landed
    AWRITE(0, 1, p0, p1, p2, p3);
    LGKM0();
    __builtin_amdgcn_s_barrier();
  }

  for (int kt = 0; kt < NKT; ++kt) {
    const int c = kt & 1, o = c ^ 1;
    const int bo_ = c << 14;             // A/B buf offset (16KB each)
    const int oo_ = o << 14;
    const bool pf = (kt + 1) < NKT;
    s16x8 aq[4], bq[4];
    f32x4 ar0, ar1, ar2, ar3;

    if (pf) ALOAD(kt + 1, 0, ar0, ar1, ar2, ar3);   // issue-early: A(k+1) H0
    FRAGS(bo_, col0);
    if (pf) STAGE_B(kt + 1, oo_);                   // B(k+1) -> LDS buf o (async)
    MFMAS();                                        // unpinned: reads pipeline in
    VMW(4);                                         // A H0 regs landed
    if (pf) { AWRITE(oo_, 0, ar0, ar1, ar2, ar3); ALOAD(kt + 1, 1, ar0, ar1, ar2, ar3); }
    FRAGS(bo_, col1);
    MFMAS();                                        // unpinned
    VMW(0);                                         // A H1 regs + B(k+1) in LDS
    if (pf) AWRITE(oo_, 1, ar0, ar1, ar2, ar3);
    LGKM0();                                        // publish my ds_writes
    __builtin_amdgcn_s_barrier();                   // buf o fully published
  }

  // ---- pure-register epilogue: acc[mf][gate][r] holds all 4 gates of
  // (m = m0 + mf*16 + r, h = (nt*2+wc)*16 + rx). 64B-coalesced per 16-lane group.
  {
    const int hq = (nt * 2 + wc) * 16 + rx;
    const float bbi = BI[hq], bbf = BF[hq], bbo = BO[hq], bbs = BSv[hq];
    const int m0 = mt * 128 + wr * 64 + (lane >> 4) * 4;
    float* outNS = out + (size_t)BS * HD;
    #pragma unroll
    for (int mf = 0; mf < 4; ++mf) {
      const int mrow = m0 + mf * 16;
      float old_[4];
      #pragma unroll
      for (int r = 0; r < 4; ++r)
        old_[r] = OLD[(size_t)(mrow + r) * HD + hq];
      #pragma unroll
      for (int r = 0; r < 4; ++r) {
        const float ig = sigmoidf_(acc[mf][0][r] + bbi);
        const float fg = sigmoidf_(acc[mf][1][r] + bbf);
        const float og = sigmoidf_(acc[mf][2][r] + bbo);
        const float cg = tanhf_(acc[mf][3][r] + bbs);
        const float ns = fg * old_[r] + ig * cg;
        const float nh = og * tanhf_(ns);
        out[(size_t)(mrow + r) * HD + hq]   = nh;
        outNS[(size_t)(mrow + r) * HD + hq] = ns;
      }
    }
  }
#undef STAGE_B
#undef ALOAD
#undef AWRITE
#undef VMW
#undef LGKM0
#undef FRAGS
#undef MFMAS
}

extern "C" void kernel_launch(void* const* d_in, const int* in_sizes, int n_in,
                              void* d_out, int out_size, void* d_ws, size_t ws_size,
                              hipStream_t stream) {
  const float* X   = (const float*)d_in[0];
  const float* PT  = (const float*)d_in[1];
  const float* PL  = (const float*)d_in[2];
  const float* OLD = (const float*)d_in[3];
  const float* Wi  = (const float*)d_in[4];
  const float* bi  = (const float*)d_in[5];
  const float* Wf  = (const float*)d_in[6];
  const float* bfv = (const float*)d_in[7];
  const float* Wo  = (const float*)d_in[8];
  const float* bo  = (const float*)d_in[9];
  const float* Ws  = (const float*)d_in[10];
  const float* bsv = (const float*)d_in[11];
  float* out = (float*)d_out;

  unsigned short* Wt = (unsigned short*)d_ws;   // 1024*1280*2 = 2.62 MB

  conv_w_kernel<<<320, 256, 0, stream>>>(Wi, Wf, Wo, Ws, Wt);
  lstm_gemm_kernel<<<1024, 256, 0, stream>>>(X, PT, PL, Wt, bi, bfv, bo, bsv, OLD, out);
}

// Round 15
// 57.988 us; speedup vs baseline: 1.2892x; 1.2892x over previous
//
#include <hip/hip_runtime.h>
#include <stdint.h>

#define BS   16384
#define XRW  768
#define HD   256
#define DIN  1280
#define N4   1024
#define NKT  20   // 1280 / 64 K-tiles

typedef __attribute__((ext_vector_type(4))) float f32x4;
typedef __attribute__((ext_vector_type(8))) short s16x8;
typedef __attribute__((ext_vector_type(4))) unsigned int u32x4;

__device__ __forceinline__ unsigned short f2bf(float f) {
  uint32_t u = __builtin_bit_cast(uint32_t, f);
  u += 0x7FFFu + ((u >> 16) & 1u);   // RNE
  return (unsigned short)(u >> 16);
}
__device__ __forceinline__ uint32_t cvtpk(float a, float b) {
  uint32_t d;
  asm("v_cvt_pk_bf16_f32 %0, %1, %2" : "=v"(d) : "v"(a), "v"(b));
  return d;
}
__device__ __forceinline__ float sigmoidf_(float x) {
  return 1.0f / (1.0f + __expf(-x));
}
__device__ __forceinline__ float tanhf_(float x) {
  return 1.0f - 2.0f / (__expf(2.0f * x) + 1.0f);
}
__device__ __forceinline__ void gload16(const void* g, void* l) {
  __builtin_amdgcn_global_load_lds((const __attribute__((address_space(1))) void*)g,
                                   (__attribute__((address_space(3))) void*)l, 16, 0, 0);
}

// ---- Wt[n'][k] bf16 row-major; n' = (h>>4)*64 + g*16 + (h&15).
// LDS-tiled transpose (R13, verified): b = g + 4*(kt + 20*ht).
__global__ __launch_bounds__(256) void conv_w_kernel(const float* __restrict__ Wi,
                                                     const float* __restrict__ Wf,
                                                     const float* __restrict__ Wo,
                                                     const float* __restrict__ Ws,
                                                     unsigned short* __restrict__ Wt) {
  __shared__ float tile[64][65];
  const int b  = blockIdx.x;
  const int g  = b & 3;                 // gate
  const int t  = b >> 2;                // [0,80)
  const int k0 = (t % 20) * 64;         // k-tile base
  const int h0 = (t / 20) * 64;         // h-tile base
  const float* W = (g == 0) ? Wi : (g == 1) ? Wf : (g == 2) ? Wo : Ws;

  const int tr = threadIdx.x >> 4;            // 0..15
  const int tc = (threadIdx.x & 15) * 4;      // 0..60
  #pragma unroll
  for (int rr = 0; rr < 4; ++rr) {
    const int r = rr * 16 + tr;
    f32x4 v = *(const f32x4*)(W + (size_t)(k0 + r) * HD + h0 + tc);
    tile[r][tc + 0] = v.x; tile[r][tc + 1] = v.y;
    tile[r][tc + 2] = v.z; tile[r][tc + 3] = v.w;
  }
  __syncthreads();

  const int hl = threadIdx.x >> 2;            // 0..63 local h
  const int kc = (threadIdx.x & 3) * 16;      // 0..48 local k chunk
  const int h  = h0 + hl;
  const int np = (h >> 4) * 64 + g * 16 + (h & 15);
  s16x8 o0, o1;
  #pragma unroll
  for (int j = 0; j < 8; ++j) {
    o0[j] = (short)f2bf(tile[kc + j][hl]);
    o1[j] = (short)f2bf(tile[kc + 8 + j][hl]);
  }
  *(s16x8*)(Wt + (size_t)np * DIN + k0 + kc)     = o0;
  *(s16x8*)(Wt + (size_t)np * DIN + k0 + kc + 8) = o1;
}

// ---- 256x256 tile, BK=64, 8 waves (2M x 4N, 128x64 each), 2-buffer LDS.
// R9/R13 champion K-loop, unchanged. Epilogue: OLD loads software-pipelined
// one mf-group ahead; nontemporal output stores (written-never-read).
__global__ __launch_bounds__(512, 2)
void lstm_gemm_kernel(const float* __restrict__ X,
                      const float* __restrict__ PT,
                      const float* __restrict__ PL,
                      const unsigned short* __restrict__ Wt,
                      const float* __restrict__ BI,
                      const float* __restrict__ BF,
                      const float* __restrict__ BO,
                      const float* __restrict__ BSv,
                      const float* __restrict__ OLD,
                      float* __restrict__ out) {
  __shared__ unsigned char smem[131072];  // A: 2x32KB @0; B: 2x32KB @64K
  const int tid  = threadIdx.x;
  const int wid  = tid >> 6;
  const int lane = tid & 63;

  // T1: XCD owns 8 contiguous M-panels x all 4 N-tiles; nt-siblings share A in L2.
  const int H = blockIdx.x;
  const int xcd = H & 7, slot = H >> 3;          // slot in [0,32)
  const int mt = xcd * 8 + (slot >> 2);          // [0,64)
  const int nt = slot & 3;                       // [0,4)
  const int wr = wid >> 2, wc = wid & 3;

  // ---- B staging (gload_lds, linear LDS dest, pre-swizzled source col)
  const int r8   = lane >> 3;
  const int scol = ((lane & 7) ^ r8) << 4;
  const char* gB = (const char*)Wt + (size_t)(nt * 256 + wid * 8 + r8) * (DIN * 2) + scol;

#define STAGE_B(t1, oB) do {                                                  \
    const int kb_ = (t1) * 128;                                               \
    _Pragma("unroll")                                                         \
    for (int c_ = 0; c_ < 4; ++c_)                                            \
      gload16(gB + (size_t)c_ * (64 * DIN * 2) + kb_,                         \
              &smem[65536 + (oB) + c_ * 8192 + wid * 1024]);                  \
  } while (0)

  // ---- A reg staging: half h covers rows h*128 + {arow, arow+64}
  const int arow  = tid >> 3;
  const int a7    = tid & 7;
  const int awcol = ((a7 ^ (arow & 7)) << 4);

#define ALOAD(t1, h, R0, R1, R2, R3) do {                                     \
    const float* asrc_; int astr_, aoff_;                                     \
    if ((t1) < 12)      { asrc_ = X;  astr_ = XRW; aoff_ = (t1) * 64; }       \
    else if ((t1) < 16) { asrc_ = PT; astr_ = HD;  aoff_ = ((t1) - 12) * 64; }\
    else                { asrc_ = PL; astr_ = HD;  aoff_ = ((t1) - 16) * 64; }\
    const float* ga_ = asrc_ + (size_t)(mt * 256 + arow + (h) * 128) * astr_  \
                             + aoff_ + a7 * 8;                                \
    R0 = *(const f32x4*)(ga_);                                                \
    R1 = *(const f32x4*)(ga_ + 4);                                            \
    R2 = *(const f32x4*)(ga_ + (size_t)64 * astr_);                           \
    R3 = *(const f32x4*)(ga_ + (size_t)64 * astr_ + 4);                       \
  } while (0)

#define AWRITE(oB, h, R0, R1, R2, R3) do {                                    \
    u32x4 w0_, w1_;                                                           \
    w0_.x = cvtpk(R0.x, R0.y); w0_.y = cvtpk(R0.z, R0.w);                     \
    w0_.z = cvtpk(R1.x, R1.y); w0_.w = cvtpk(R1.z, R1.w);                     \
    w1_.x = cvtpk(R2.x, R2.y); w1_.y = cvtpk(R2.z, R2.w);                     \
    w1_.z = cvtpk(R3.x, R3.y); w1_.w = cvtpk(R3.z, R3.w);                     \
    *(u32x4*)(&smem[(oB) + ((arow + (h) * 128)      << 7) + awcol]) = w0_;    \
    *(u32x4*)(&smem[(oB) + ((arow + (h) * 128 + 64) << 7) + awcol]) = w1_;    \
  } while (0)

  // ---- frag read addressing (row&7 == lane&7 for all frags)
  const int rx   = lane & 15;
  const int axor = (lane & 7) << 4;
  const int col0 = (((lane >> 4) << 4)) ^ axor;        // kh=0
  const int col1 = (64 + ((lane >> 4) << 4)) ^ axor;   // kh=1
  const int aRow = (wr * 128 + rx) * 128;              // + mf*2048
  const int bRow = 65536 + (wc * 64 + rx) * 128;       // + nf*2048

  f32x4 acc[8][4];
  #pragma unroll
  for (int i = 0; i < 8; ++i)
    #pragma unroll
    for (int j = 0; j < 4; ++j) {
      f32x4 z = {0.0f, 0.0f, 0.0f, 0.0f};
      acc[i][j] = z;
    }

#define VMW(N) asm volatile("s_waitcnt vmcnt(" #N ")" ::: "memory")
#define LGKM0() do { asm volatile("s_waitcnt lgkmcnt(0)" ::: "memory");       \
                     __builtin_amdgcn_sched_barrier(0); } while (0)
  // bq FIRST: first MFMA needs bq[0..3]+aq[0]; remaining aq reads hide
  // under the MFMA stream (compiler emits per-register lgkmcnt).
#define FRAGS(bo_, kh_col) do {                                               \
    _Pragma("unroll")                                                         \
    for (int nf = 0; nf < 4; ++nf)                                            \
      bq[nf] = *(const s16x8*)(&smem[(bo_) + bRow + nf * 2048 + (kh_col)]);   \
    _Pragma("unroll")                                                         \
    for (int mf = 0; mf < 8; ++mf)                                            \
      aq[mf] = *(const s16x8*)(&smem[(bo_) + aRow + mf * 2048 + (kh_col)]);   \
  } while (0)
#define MFMAS() do {                                                          \
    __builtin_amdgcn_s_setprio(1);                                            \
    _Pragma("unroll")                                                         \
    for (int mf = 0; mf < 8; ++mf)                                            \
      _Pragma("unroll")                                                       \
      for (int nf = 0; nf < 4; ++nf)                                          \
        acc[mf][nf] = __builtin_amdgcn_mfma_f32_16x16x32_bf16(aq[mf], bq[nf], \
                                                      acc[mf][nf], 0, 0, 0);  \
    __builtin_amdgcn_s_setprio(0);                                            \
  } while (0)

  // ---- prologue: fill buf0 with tile 0 (A via regs+cvt, B via gload_lds)
  {
    f32x4 p0, p1, p2, p3;
    ALOAD(0, 0, p0, p1, p2, p3);
    STAGE_B(0, 0);
    VMW(4);        // A H0 regs landed (B(0) in flight)
    AWRITE(0, 0, p0, p1, p2, p3);
    ALOAD(0, 1, p0, p1, p2, p3);
    VMW(0);        // A H1 + B(0) landed
    AWRITE(0, 1, p0, p1, p2, p3);
    LGKM0();
    __builtin_amdgcn_s_barrier();
  }

  for (int kt = 0; kt < NKT; ++kt) {
    const int c = kt & 1, o = c ^ 1;
    const int bo_ = c << 15;
    const int oo_ = o << 15;
    const bool pf = (kt + 1) < NKT;
    s16x8 aq[8], bq[4];
    f32x4 ar0, ar1, ar2, ar3;

    if (pf) ALOAD(kt + 1, 0, ar0, ar1, ar2, ar3);   // issue-early: A(k+1) H0
    FRAGS(bo_, col0);
    if (pf) STAGE_B(kt + 1, oo_);                   // B(k+1) -> LDS buf o (async)
    MFMAS();                                        // unpinned: reads pipeline in
    VMW(4);                                         // A H0 regs landed
    if (pf) { AWRITE(oo_, 0, ar0, ar1, ar2, ar3); ALOAD(kt + 1, 1, ar0, ar1, ar2, ar3); }
    FRAGS(bo_, col1);
    MFMAS();                                        // unpinned
    VMW(0);                                         // A H1 regs + B(k+1) in LDS
    if (pf) AWRITE(oo_, 1, ar0, ar1, ar2, ar3);
    LGKM0();                                        // publish my ds_writes
    __builtin_amdgcn_s_barrier();                   // buf o fully published
  }

  // ---- pure-register epilogue, OLD software-pipelined one mf-group ahead;
  // nontemporal stores (outputs are written-never-read).
  {
    const int hq = nt * 64 + wc * 16 + rx;
    const float bbi = BI[hq], bbf = BF[hq], bbo = BO[hq], bbs = BSv[hq];
    const int m0 = mt * 256 + wr * 128 + (lane >> 4) * 4;
    float* outNS = out + (size_t)BS * HD;
    float oldc[4], oldn[4];
    #pragma unroll
    for (int r = 0; r < 4; ++r)
      oldc[r] = OLD[(size_t)(m0 + r) * HD + hq];
    #pragma unroll
    for (int mf = 0; mf < 8; ++mf) {
      const int mrow = m0 + mf * 16;
      if (mf < 7) {
        #pragma unroll
        for (int r = 0; r < 4; ++r)
          oldn[r] = OLD[(size_t)(mrow + 16 + r) * HD + hq];   // prefetch next
      }
      #pragma unroll
      for (int r = 0; r < 4; ++r) {
        const float ig = sigmoidf_(acc[mf][0][r] + bbi);
        const float fg = sigmoidf_(acc[mf][1][r] + bbf);
        const float og = sigmoidf_(acc[mf][2][r] + bbo);
        const float cg = tanhf_(acc[mf][3][r] + bbs);
        const float ns = fg * oldc[r] + ig * cg;
        const float nh = og * tanhf_(ns);
        __builtin_nontemporal_store(nh, &out[(size_t)(mrow + r) * HD + hq]);
        __builtin_nontemporal_store(ns, &outNS[(size_t)(mrow + r) * HD + hq]);
      }
      #pragma unroll
      for (int r = 0; r < 4; ++r)
        oldc[r] = oldn[r];
    }
  }
#undef STAGE_B
#undef ALOAD
#undef AWRITE
#undef VMW
#undef LGKM0
#undef FRAGS
#undef MFMAS
}

extern "C" void kernel_launch(void* const* d_in, const int* in_sizes, int n_in,
                              void* d_out, int out_size, void* d_ws, size_t ws_size,
                              hipStream_t stream) {
  const float* X   = (const float*)d_in[0];
  const float* PT  = (const float*)d_in[1];
  const float* PL  = (const float*)d_in[2];
  const float* OLD = (const float*)d_in[3];
  const float* Wi  = (const float*)d_in[4];
  const float* bi  = (const float*)d_in[5];
  const float* Wf  = (const float*)d_in[6];
  const float* bfv = (const float*)d_in[7];
  const float* Wo  = (const float*)d_in[8];
  const float* bo  = (const float*)d_in[9];
  const float* Ws  = (const float*)d_in[10];
  const float* bsv = (const float*)d_in[11];
  float* out = (float*)d_out;

  unsigned short* Wt = (unsigned short*)d_ws;   // 1024*1280*2 = 2.62 MB

  conv_w_kernel<<<320, 256, 0, stream>>>(Wi, Wf, Wo, Ws, Wt);
  lstm_gemm_kernel<<<256, 512, 0, stream>>>(X, PT, PL, Wt, bi, bfv, bo, bsv, OLD, out);
}